// Round 8
// baseline (159.599 us; speedup 1.0000x reference)
//
#include <hip/hip_runtime.h>

#define G_ 100
#define T_ 24
#define GP1 101
#define TILE (G_ * T_)        // 2400 floats per (b,pass) tile
#define VPB (TILE / 4)        // 600 float4 per tile
#define WPB 4                 // waves per block: 2 b's x 2 passes
#define BLOCK (64 * WPB)      // 256 threads

typedef float vfloat4 __attribute__((ext_vector_type(4)));

// In-LDS merit-order chunk: N conflict-free ds_reads issued as one batched
// flight (independent addresses), then the serial clip-scan in VALU, then
// N ds_writes (alloc overwrites cap row in place; every row is touched by
// exactly one rank -> no RAW hazard across batches).
// ord/price come from per-wave registers via v_readlane (uniform -> SGPR,
// exec-mask-ignoring, safe under the lane<24 divergent branch).
template<int N>
__device__ __forceinline__ void lds_scan_chunk(int k0,
    float* __restrict__ tw, int t,
    int ord_lo, int ord_hi, float pr_lo, float pr_hi,
    float dem, float& before, float& objp)
{
    int gg[N]; float pr[N], cap[N];
#pragma unroll
    for (int j = 0; j < N; ++j) {
        const int idx = k0 + j;              // compile-time constant
        if (idx < 64) {
            gg[j] = __builtin_amdgcn_readlane(ord_lo, idx);
            pr[j] = __int_as_float(__builtin_amdgcn_readlane(__float_as_int(pr_lo), idx));
        } else {
            gg[j] = __builtin_amdgcn_readlane(ord_hi, idx - 64);
            pr[j] = __int_as_float(__builtin_amdgcn_readlane(__float_as_int(pr_hi), idx - 64));
        }
    }
#pragma unroll
    for (int j = 0; j < N; ++j) cap[j] = tw[gg[j] * T_ + t];  // batched ds_reads
#pragma unroll
    for (int j = 0; j < N; ++j) {
        float a = fminf(fmaxf(dem - before, 0.f), cap[j]);
        before += cap[j];
        objp = fmaf(pr[j], a, objp);
        tw[gg[j] * T_ + t] = a;              // in-place, conflict-free
    }
}

__global__ __launch_bounds__(BLOCK, 4) void dispatch_kernel(
    const float* __restrict__ R_up, const float* __restrict__ R_dn,
    const float* __restrict__ omega,
    const float* __restrict__ b_G, const float* __restrict__ voll,
    const float* __restrict__ vosp, const float* __restrict__ ru,
    const float* __restrict__ rd,
    float* __restrict__ out, int B)
{
    __shared__ float s_tile[WPB * TILE];   // 38400 B -> 4 blocks/CU, 16 waves
    __shared__ float s_obj[WPB];

    const int tid  = threadIdx.x;
    const int w    = tid >> 6;
    const int lane = tid & 63;
    const int b = __builtin_amdgcn_readfirstlane(blockIdx.x * 2 + (w >> 1));
    const int p = __builtin_amdgcn_readfirstlane(w & 1);
    const size_t bgt = (size_t)B * TILE;

    // ---- 0. issue the ENTIRE cap tile load FIRST: 10 coalesced float4
    // (1KB/inst) per lane; the flight drains under the sort ----
    const vfloat4* __restrict__ s4 =
        (const vfloat4*)((p ? R_dn : R_up) + (size_t)b * TILE);
    vfloat4 v[9]; vfloat4 vt;
#pragma unroll
    for (int j = 0; j < 9; ++j) v[j] = s4[lane + j * 64];
    if (lane < VPB - 576) vt = s4[lane + 576];
    float om = 0.f;
    if (lane < T_) om = omega[(size_t)b * T_ + lane];

    // ---- 1. fused merit-order sort (== stable jnp.argsort of prices),
    // scratch aliased into wave0's tile region (dead until staging) ----
    float* s_praw = s_tile;                 // [2][128] floats @ [0,256)
    int*   s_ord  = (int*)&s_tile[256];     // [2][128] ints   @ [256,512)
    float* s_pr   = &s_tile[512];           // [2][128] floats @ [512,768)
    {   // pass 0 on tid<128, pass 1 on tid>=128 -> parallel waves
        const int sp = tid >> 7;
        const int si = tid & 127;
        if (si < GP1) {
            float m;
            if (si < G_) m = (sp ? rd[0] : ru[0]) * b_G[si];
            else         m = sp ? vosp[0] : voll[0];
            s_praw[sp * 128 + si] = m;
        }
        __syncthreads();
        if (si < GP1) {
            const float m = s_praw[sp * 128 + si];
            int r = 0;
#pragma unroll
            for (int j = 0; j < GP1; ++j) {
                const float vv = s_praw[sp * 128 + j];
                r += (vv < m) || (vv == m && j < si);
            }
            s_ord[sp * 128 + r] = si;
            s_pr [sp * 128 + r] = m;
        }
    }
    __syncthreads();

    // ---- 2. cache this wave's sorted merit order in registers ----
    const int hi_ok = (lane < GP1 - 64);
    const int   ord_lo = s_ord[p * 128 + lane];
    const int   ord_hi = hi_ok ? s_ord[p * 128 + 64 + lane] : 0;
    const float pr_lo  = s_pr [p * 128 + lane];
    const float pr_hi  = hi_ok ? s_pr [p * 128 + 64 + lane] : 0.f;
    __syncthreads();                        // scratch consumed -> tile reuse ok

    // ---- 3. stage the staged registers into the wave-private LDS tile ----
    float* __restrict__ tw = &s_tile[w * TILE];
#pragma unroll
    for (int j = 0; j < 9; ++j) *(vfloat4*)&tw[(lane + j * 64) * 4] = v[j];
    if (lane < VPB - 576) *(vfloat4*)&tw[(lane + 576) * 4] = vt;
    __builtin_amdgcn_wave_barrier();        // pin ds_write -> ds_read order

    // ---- 4. unconditional 100-rank scan from LDS, 16-deep batched flights
    // (no ballots, no gating; allocs past k* are exactly 0) ----
    float objp = 0.f;
    if (lane < T_) {
        const int t = lane;
        const float dem = p ? fmaxf(-om, 0.f) : fmaxf(om, 0.f);
        float before = 0.f;
        lds_scan_chunk<16>( 0, tw, t, ord_lo, ord_hi, pr_lo, pr_hi, dem, before, objp);
        lds_scan_chunk<16>(16, tw, t, ord_lo, ord_hi, pr_lo, pr_hi, dem, before, objp);
        lds_scan_chunk<16>(32, tw, t, ord_lo, ord_hi, pr_lo, pr_hi, dem, before, objp);
        lds_scan_chunk<16>(48, tw, t, ord_lo, ord_hi, pr_lo, pr_hi, dem, before, objp);
        lds_scan_chunk<16>(64, tw, t, ord_lo, ord_hi, pr_lo, pr_hi, dem, before, objp);
        lds_scan_chunk<16>(80, tw, t, ord_lo, ord_hi, pr_lo, pr_hi, dem, before, objp);
        lds_scan_chunk< 4>(96, tw, t, ord_lo, ord_hi, pr_lo, pr_hi, dem, before, objp);

        // slack (rank 100): clip(dem - sum_all_caps, 0, dem)
        const float slack_pr =
            __int_as_float(__builtin_amdgcn_readlane(__float_as_int(pr_hi), GP1 - 1 - 64));
        const float slackv = fmaxf(dem - before, 0.f);
        objp = fmaf(slack_pr, slackv, objp);
        out[2 * bgt + (size_t)p * B * T_ + (size_t)b * T_ + t] = slackv;
    }

    // ---- rt_obj partial: butterfly over the wave (idle lanes hold 0) ----
#pragma unroll
    for (int off = 32; off; off >>= 1) objp += __shfl_xor(objp, off, 64);
    if (lane == 0) s_obj[w] = objp;

    // ---- 5. stream the finished tile out, fully coalesced float4 ----
    __builtin_amdgcn_wave_barrier();        // pin scan ds_writes -> ds_reads
    {
        vfloat4* __restrict__ dst = (vfloat4*)out + ((size_t)p * B + b) * VPB;
#pragma unroll
        for (int j = 0; j < 9; ++j)
            dst[lane + j * 64] = *(const vfloat4*)&tw[(lane + j * 64) * 4];
        if (lane < VPB - 576)
            dst[lane + 576] = *(const vfloat4*)&tw[(lane + 576) * 4];
    }

    // ---- pair up+dn partials per b (barrier hides under stream-out) ----
    __syncthreads();
    if (tid == 0)
        out[2 * bgt + 2 * (size_t)B * T_ + b] = s_obj[0] + s_obj[1];
    if (tid == 128)
        out[2 * bgt + 2 * (size_t)B * T_ + b] = s_obj[2] + s_obj[3];
}

extern "C" void kernel_launch(void* const* d_in, const int* in_sizes, int n_in,
                              void* d_out, int out_size, void* d_ws, size_t ws_size,
                              hipStream_t stream)
{
    const float* R_up  = (const float*)d_in[0];
    const float* R_dn  = (const float*)d_in[1];
    const float* omega = (const float*)d_in[2];
    const float* b_G   = (const float*)d_in[3];
    const float* voll  = (const float*)d_in[4];
    const float* vosp  = (const float*)d_in[5];
    const float* ru    = (const float*)d_in[6];
    const float* rd    = (const float*)d_in[7];

    const int B = in_sizes[0] / TILE;
    float* out = (float*)d_out;

    // single fused launch: 4 waves/block = 2 b's x 2 passes; grid B/2
    dispatch_kernel<<<B / 2, BLOCK, 0, stream>>>(
        R_up, R_dn, omega, b_G, voll, vosp, ru, rd, out, B);
}